// Round 5
// baseline (654.806 us; speedup 1.0000x reference)
//
#include <hip/hip_runtime.h>
#include <hip/hip_bf16.h>
#include <stdint.h>

#define B_ 2
#define N_ 20000
#define H_ 256
#define E_ 160000
#define M_ 512

typedef short bf16x8 __attribute__((ext_vector_type(8)));
typedef float f32x4 __attribute__((ext_vector_type(4)));

__device__ __forceinline__ unsigned short f2bf(float f) {
    union { float f; unsigned u; } cv; cv.f = f;
    unsigned u = cv.u;
    unsigned r = u + 0x7fffu + ((u >> 16) & 1u);
    return (unsigned short)(r >> 16);
}
__device__ __forceinline__ unsigned pack2(float a, float b) {
    return (unsigned)f2bf(a) | ((unsigned)f2bf(b) << 16);
}
__device__ __forceinline__ float bflo(unsigned p) {
    union { unsigned u; float f; } c; c.u = p << 16; return c.f;
}
__device__ __forceinline__ float bfhi(unsigned p) {
    union { unsigned u; float f; } c; c.u = p & 0xffff0000u; return c.f;
}

// ---------- merged weight transpose/convert ----------
__device__ __forceinline__ void conv_t_one(const float* __restrict__ W,
                                           unsigned short* __restrict__ Wt,
                                           int K, int Ncol, int idx) {
    int n = idx % Ncol;
    int kc = (idx / Ncol) << 3;
    unsigned short t[8];
#pragma unroll
    for (int j = 0; j < 8; ++j) t[j] = f2bf(W[(size_t)(kc + j) * Ncol + n]);
    uint4 v;
    v.x = (unsigned)t[0] | ((unsigned)t[1] << 16);
    v.y = (unsigned)t[2] | ((unsigned)t[3] << 16);
    v.z = (unsigned)t[4] | ((unsigned)t[5] << 16);
    v.w = (unsigned)t[6] | ((unsigned)t[7] << 16);
    *(uint4*)(Wt + (size_t)n * K + kc) = v;
}

// W1pq[jj][kk]: jj<512 -> P col: W1[kk][jj]; jj>=512 -> Q col: W1[kk+256][jj-512]
__device__ __forceinline__ void conv_w1pq_one(const float* __restrict__ W,
                                              unsigned short* __restrict__ Wt, int idx) {
    int jj = idx & 1023;
    int kc = (idx >> 10) << 3;
    int koff = (jj >= 512) ? 256 : 0;
    int j = jj & 511;
    unsigned short t[8];
#pragma unroll
    for (int r = 0; r < 8; ++r) t[r] = f2bf(W[(size_t)(kc + r + koff) * 512 + j]);
    uint4 v;
    v.x = (unsigned)t[0] | ((unsigned)t[1] << 16);
    v.y = (unsigned)t[2] | ((unsigned)t[3] << 16);
    v.z = (unsigned)t[4] | ((unsigned)t[5] << 16);
    v.w = (unsigned)t[6] | ((unsigned)t[7] << 16);
    *(uint4*)(Wt + (size_t)jj * 256 + kc) = v;
}

__global__ void conv_all(const float* __restrict__ mw1, const float* __restrict__ mw2,
                         const float* __restrict__ uw1, const float* __restrict__ uw2,
                         unsigned short* __restrict__ w1pq, unsigned short* __restrict__ w2t,
                         unsigned short* __restrict__ u1t, unsigned short* __restrict__ u2t) {
    int idx = blockIdx.x * blockDim.x + threadIdx.x;
    if (idx < 32768) {
        conv_w1pq_one(mw1, w1pq, idx);
    } else if (idx < 49152) {
        conv_t_one(mw2, w2t, 512, 256, idx - 32768);
    } else if (idx < 81920) {
        conv_t_one(uw1, u1t, 512, 512, idx - 49152);
    } else if (idx < 98304) {
        conv_t_one(uw2, u2t, 512, 256, idx - 81920);
    }
}

// ---------- edge sort by dst (counting sort; store SRC directly) ----------
__global__ void hist_kernel(const int* __restrict__ eidx, int* __restrict__ cnt) {
    for (int e = blockIdx.x * blockDim.x + threadIdx.x; e < E_;
         e += gridDim.x * blockDim.x)
        atomicAdd(cnt + eidx[E_ + e], 1);
}

__global__ void scan_kernel(const int* __restrict__ cnt, int* __restrict__ offs,
                            int* __restrict__ cursor) {
    __shared__ int part[1024];
    int t = threadIdx.x;
    int base_i = t * 20;
    int loc[20];
    int s = 0;
#pragma unroll 20
    for (int i = 0; i < 20; ++i) {
        int idx = base_i + i;
        int v = (idx < N_) ? cnt[idx] : 0;
        loc[i] = s;
        s += v;
    }
    part[t] = s;
    __syncthreads();
    for (int off = 1; off < 1024; off <<= 1) {
        int tmp = (t >= off) ? part[t - off] : 0;
        __syncthreads();
        if (t >= off) part[t] += tmp;
        __syncthreads();
    }
    int base = part[t] - s;
#pragma unroll 20
    for (int i = 0; i < 20; ++i) {
        int idx = base_i + i;
        if (idx < N_) {
            int o = base + loc[i];
            offs[idx] = o;
            cursor[idx] = o;
        }
    }
    if (t == 1023) offs[N_] = part[1023];
}

__global__ void scatter_kernel(const int* __restrict__ eidx, int* __restrict__ cursor,
                               int* __restrict__ srcs) {
    for (int e = blockIdx.x * blockDim.x + threadIdx.x; e < E_;
         e += gridDim.x * blockDim.x) {
        int d = eidx[E_ + e];
        int pos = atomicAdd(cursor + d, 1);
        srcs[pos] = eidx[e];
    }
}

// ---------- PQ = h_b @ [W1a | W1b]  (20000 rows, K=256, 1024 cols) ----------
__global__ __launch_bounds__(512, 4) void pq_gemm(
    const float* __restrict__ hb,
    const unsigned short* __restrict__ W1pq,  // [1024][256] bf16
    unsigned short* __restrict__ PQ) {        // [20000][1024] bf16
    __shared__ char smem[32 * 512];  // 16 KB
    const int tid = threadIdx.x;
    const int tile = blockIdx.x >> 1;
    const int qh = blockIdx.x & 1;
    const int row0 = tile * 32;

#pragma unroll
    for (int it = 0; it < 4; ++it) {
        int linear = it * 512 + tid;
        int row = linear >> 6;
        int c4 = linear & 63;
        float4 v = *(const float4*)(hb + (size_t)(row0 + row) * H_ + c4 * 4);
        int byte = (row * 512 + c4 * 8) ^ ((row & 7) << 4);
        uint2 p;
        p.x = pack2(v.x, v.y);
        p.y = pack2(v.z, v.w);
        *(uint2*)(smem + byte) = p;
    }
    __syncthreads();

    const int lane = tid & 63;
    const int w = tid >> 6;
    const int lo = lane & 15;
    const int hi = lane >> 4;
    const int colw = qh * 512 + w * 64;

    f32x4 acc[2][4];
#pragma unroll
    for (int i = 0; i < 2; ++i)
#pragma unroll
        for (int j = 0; j < 4; ++j) acc[i][j] = (f32x4){0.f, 0.f, 0.f, 0.f};

#pragma unroll 4
    for (int ks = 0; ks < 256; ks += 32) {
        bf16x8 af[2];
#pragma unroll
        for (int rf = 0; rf < 2; ++rf) {
            int row = rf * 16 + lo;
            int byte = (row * 512 + (ks + 8 * hi) * 2) ^ ((row & 7) << 4);
            af[rf] = *(const bf16x8*)(smem + byte);
        }
#pragma unroll
        for (int cf = 0; cf < 4; ++cf) {
            bf16x8 bfr = *(const bf16x8*)(W1pq + (size_t)(colw + cf * 16 + lo) * 256 + ks + 8 * hi);
#pragma unroll
            for (int rf = 0; rf < 2; ++rf)
                acc[rf][cf] = __builtin_amdgcn_mfma_f32_16x16x32_bf16(af[rf], bfr, acc[rf][cf], 0, 0, 0);
        }
    }

#pragma unroll
    for (int cf = 0; cf < 4; ++cf) {
        int col = colw + cf * 16 + lo;
#pragma unroll
        for (int rf = 0; rf < 2; ++rf) {
#pragma unroll
            for (int r = 0; r < 4; ++r) {
                int row = rf * 16 + hi * 4 + r;
                PQ[(size_t)(row0 + row) * 1024 + col] = f2bf(acc[rf][cf][r]);
            }
        }
    }
}

// ---------- fused aggregate + msg-GEMM2 + update MLP ----------
// block: 16 dsts, 512 threads, LDS = smA(16KB) + smB(16KB) -> 4 blocks/CU
// A: edge gather (32 lanes/dst, 16 cols each) -> hidden-sum (smA); h staged to smB left
// B: agg = hiddensum @ W2 + deg*mb2 -> smB right (bf16)
// C: hid2 = relu([h|agg] @ U1 + ub1) -> smA
// D: out = h + hid2 @ U2 + ub2
__global__ __launch_bounds__(512, 8) void aggupd_kernel(
    const unsigned short* __restrict__ PQ,
    const int* __restrict__ srcs,
    const int* __restrict__ offs,
    const int* __restrict__ cnt,
    const unsigned short* __restrict__ w2t,   // [256][512]
    const float* __restrict__ mb1,
    const float* __restrict__ mb2,
    const unsigned short* __restrict__ u1t,   // [512][512]
    const float* __restrict__ ub1,
    const unsigned short* __restrict__ u2t,   // [256][512]
    const float* __restrict__ ub2,
    const float* __restrict__ hb,
    float* __restrict__ outb) {
    __shared__ char smA[16 * 1024];
    __shared__ char smB[16 * 1024];
    __shared__ int s_cnt[16];

    const int tid = threadIdx.x;
    const int d0 = blockIdx.x * 16;

    if (tid < 16) s_cnt[tid] = cnt[d0 + tid];

    // ---- stage h rows -> smB left half: 16 rows x 32 16B-chunks, one chunk/thread ----
    {
        int row = tid >> 5;
        int c8 = tid & 31;
        const float* src = hb + (size_t)(d0 + row) * H_ + c8 * 8;
        float4 a = *(const float4*)src;
        float4 b = *(const float4*)(src + 4);
        uint4 v;
        v.x = pack2(a.x, a.y);
        v.y = pack2(a.z, a.w);
        v.z = pack2(b.x, b.y);
        v.w = pack2(b.z, b.w);
        int byte = (row * 1024 + c8 * 16) ^ ((row & 7) << 4);
        *(uint4*)(smB + byte) = v;
    }

    // ---- phase A: edge aggregation; 32 lanes per dst, 16 cols (2 chunks) per lane ----
    const int dsub = tid >> 5;   // 0..15
    const int part = tid & 31;   // 0..31
    const int d = d0 + dsub;

    unsigned qb[8];
    {
        const unsigned short* qrow = PQ + (size_t)d * 1024 + 512;
#pragma unroll
        for (int c = 0; c < 2; ++c) {
            int cb = (c * 32 + part) * 8;
            bf16x8 qv = *(const bf16x8*)(qrow + cb);
#pragma unroll
            for (int jp = 0; jp < 4; ++jp) {
                float q0 = bflo((unsigned)(unsigned short)qv[jp * 2]) + mb1[cb + jp * 2];
                float q1 = bflo((unsigned)(unsigned short)qv[jp * 2 + 1]) + mb1[cb + jp * 2 + 1];
                qb[c * 4 + jp] = pack2(q0, q1);
            }
        }
    }

    float acc[16];
#pragma unroll
    for (int i = 0; i < 16; ++i) acc[i] = 0.f;

    const int beg = offs[d];
    const int end = offs[d + 1];
    int p = beg;
    for (; p + 1 < end; p += 2) {
        int s0 = srcs[p];
        int s1 = srcs[p + 1];
        const unsigned short* r0 = PQ + (size_t)s0 * 1024;
        const unsigned short* r1 = PQ + (size_t)s1 * 1024;
        bf16x8 v0[2], v1[2];
#pragma unroll
        for (int c = 0; c < 2; ++c) {
            v0[c] = *(const bf16x8*)(r0 + (c * 32 + part) * 8);
            v1[c] = *(const bf16x8*)(r1 + (c * 32 + part) * 8);
        }
#pragma unroll
        for (int c = 0; c < 2; ++c) {
#pragma unroll
            for (int jp = 0; jp < 4; ++jp) {
                unsigned q = qb[c * 4 + jp];
                float ql = bflo(q), qh2 = bfhi(q);
                acc[c * 8 + jp * 2] += fmaxf(bflo((unsigned)(unsigned short)v0[c][jp * 2]) + ql, 0.f)
                                     + fmaxf(bflo((unsigned)(unsigned short)v1[c][jp * 2]) + ql, 0.f);
                acc[c * 8 + jp * 2 + 1] += fmaxf(bflo((unsigned)(unsigned short)v0[c][jp * 2 + 1]) + qh2, 0.f)
                                         + fmaxf(bflo((unsigned)(unsigned short)v1[c][jp * 2 + 1]) + qh2, 0.f);
            }
        }
    }
    if (p < end) {
        int s0 = srcs[p];
        const unsigned short* r0 = PQ + (size_t)s0 * 1024;
#pragma unroll
        for (int c = 0; c < 2; ++c) {
            bf16x8 v0 = *(const bf16x8*)(r0 + (c * 32 + part) * 8);
#pragma unroll
            for (int jp = 0; jp < 4; ++jp) {
                unsigned q = qb[c * 4 + jp];
                acc[c * 8 + jp * 2]     += fmaxf(bflo((unsigned)(unsigned short)v0[jp * 2]) + bflo(q), 0.f);
                acc[c * 8 + jp * 2 + 1] += fmaxf(bflo((unsigned)(unsigned short)v0[jp * 2 + 1]) + bfhi(q), 0.f);
            }
        }
    }

#pragma unroll
    for (int c = 0; c < 2; ++c) {
        uint4 v;
        v.x = pack2(acc[c * 8 + 0], acc[c * 8 + 1]);
        v.y = pack2(acc[c * 8 + 2], acc[c * 8 + 3]);
        v.z = pack2(acc[c * 8 + 4], acc[c * 8 + 5]);
        v.w = pack2(acc[c * 8 + 6], acc[c * 8 + 7]);
        int byte = (dsub * 1024 + (c * 32 + part) * 16) ^ ((dsub & 7) << 4);
        *(uint4*)(smA + byte) = v;
    }
    __syncthreads();  // smA (hidden-sum) + smB left (h) + s_cnt ready

    const int lane = tid & 63;
    const int w = tid >> 6;
    const int lo = lane & 15;
    const int hi = lane >> 4;

    // ---- phase B: agg = hiddensum @ W2 + deg*mb2 -> smB right half ----
    {
        const int colw = w * 32;
        f32x4 a2[2];
#pragma unroll
        for (int j = 0; j < 2; ++j) a2[j] = (f32x4){0.f, 0.f, 0.f, 0.f};

        for (int ks = 0; ks < 512; ks += 32) {
            int byte = (lo * 1024 + (ks + 8 * hi) * 2) ^ ((lo & 7) << 4);
            bf16x8 af = *(const bf16x8*)(smA + byte);
#pragma unroll
            for (int cf = 0; cf < 2; ++cf) {
                bf16x8 bfr = *(const bf16x8*)(w2t + (size_t)(colw + cf * 16 + lo) * 512 + ks + 8 * hi);
                a2[cf] = __builtin_amdgcn_mfma_f32_16x16x32_bf16(af, bfr, a2[cf], 0, 0, 0);
            }
        }

#pragma unroll
        for (int cf = 0; cf < 2; ++cf) {
            int col = colw + cf * 16 + lo;
            float bb = mb2[col];
#pragma unroll
            for (int r = 0; r < 4; ++r) {
                int row = hi * 4 + r;
                float v = a2[cf][r] + (float)s_cnt[row] * bb;
                int byte = (row * 1024 + (256 + col) * 2) ^ ((row & 7) << 4);
                *(unsigned short*)(smB + byte) = f2bf(v);
            }
        }
    }
    __syncthreads();  // smB = X = [h | agg]; smA reads done

    // ---- phase C: hid2 = relu(X @ U1 + ub1) -> smA ----
    {
        const int colw = w * 64;
        f32x4 a1[4];
#pragma unroll
        for (int j = 0; j < 4; ++j) a1[j] = (f32x4){0.f, 0.f, 0.f, 0.f};

        for (int ks = 0; ks < 512; ks += 32) {
            int byte = (lo * 1024 + (ks + 8 * hi) * 2) ^ ((lo & 7) << 4);
            bf16x8 af = *(const bf16x8*)(smB + byte);
#pragma unroll
            for (int cf = 0; cf < 4; ++cf) {
                bf16x8 bfr = *(const bf16x8*)(u1t + (size_t)(colw + cf * 16 + lo) * 512 + ks + 8 * hi);
                a1[cf] = __builtin_amdgcn_mfma_f32_16x16x32_bf16(af, bfr, a1[cf], 0, 0, 0);
            }
        }

#pragma unroll
        for (int cf = 0; cf < 4; ++cf) {
            int col = colw + cf * 16 + lo;
            float bb = ub1[col];
#pragma unroll
            for (int r = 0; r < 4; ++r) {
                float v = fmaxf(a1[cf][r] + bb, 0.f);
                int row = hi * 4 + r;
                int byte = (row * 1024 + col * 2) ^ ((row & 7) << 4);
                *(unsigned short*)(smA + byte) = f2bf(v);
            }
        }
    }
    __syncthreads();

    // ---- phase D: out = h + hid2 @ U2 + ub2 ----
    {
        const int colw = w * 32;
        f32x4 a2[2];
#pragma unroll
        for (int j = 0; j < 2; ++j) a2[j] = (f32x4){0.f, 0.f, 0.f, 0.f};

        for (int ks = 0; ks < 512; ks += 32) {
            int byte = (lo * 1024 + (ks + 8 * hi) * 2) ^ ((lo & 7) << 4);
            bf16x8 af = *(const bf16x8*)(smA + byte);
#pragma unroll
            for (int cf = 0; cf < 2; ++cf) {
                bf16x8 bfr = *(const bf16x8*)(u2t + (size_t)(colw + cf * 16 + lo) * 512 + ks + 8 * hi);
                a2[cf] = __builtin_amdgcn_mfma_f32_16x16x32_bf16(af, bfr, a2[cf], 0, 0, 0);
            }
        }

#pragma unroll
        for (int cf = 0; cf < 2; ++cf) {
            int col = colw + cf * 16 + lo;
            float bb = ub2[col];
#pragma unroll
            for (int r = 0; r < 4; ++r) {
                int row = hi * 4 + r;
                size_t o = (size_t)(d0 + row) * H_ + col;
                outb[o] = hb[o] + a2[cf][r] + bb;
            }
        }
    }
}

extern "C" void kernel_launch(void* const* d_in, const int* in_sizes, int n_in,
                              void* d_out, int out_size, void* d_ws, size_t ws_size,
                              hipStream_t stream) {
    const float* h      = (const float*)d_in[0];
    const int*   eidx   = (const int*)d_in[1];
    const float* msg_w1 = (const float*)d_in[2];
    const float* msg_b1 = (const float*)d_in[3];
    const float* msg_w2 = (const float*)d_in[4];
    const float* msg_b2 = (const float*)d_in[5];
    const float* upd_w1 = (const float*)d_in[6];
    const float* upd_b1 = (const float*)d_in[7];
    const float* upd_w2 = (const float*)d_in[8];
    const float* upd_b2 = (const float*)d_in[9];
    float* out = (float*)d_out;

    char* ws = (char*)d_ws;
    size_t off = 0;
    auto alloc = [&](size_t bytes) {
        char* p = ws + off;
        off = (off + bytes + 255) & ~(size_t)255;
        return p;
    };
    unsigned short* PQ   = (unsigned short*)alloc((size_t)N_ * 1024 * 2);  // 41 MB, reused per batch
    unsigned short* w1pq = (unsigned short*)alloc(1024 * 256 * 2);
    unsigned short* w2t  = (unsigned short*)alloc(256 * 512 * 2);
    unsigned short* u1t  = (unsigned short*)alloc(512 * 512 * 2);
    unsigned short* u2t  = (unsigned short*)alloc(256 * 512 * 2);
    int* cnt    = (int*)alloc(N_ * 4);
    int* offs   = (int*)alloc((N_ + 1) * 4);
    int* cursor = (int*)alloc(N_ * 4);
    int* srcs   = (int*)alloc(E_ * 4);
    if (ws_size < off) return;

    hipMemsetAsync(cnt, 0, N_ * 4, stream);
    conv_all<<<384, 256, 0, stream>>>(msg_w1, msg_w2, upd_w1, upd_w2, w1pq, w2t, u1t, u2t);

    hist_kernel<<<256, 256, 0, stream>>>(eidx, cnt);
    scan_kernel<<<1, 1024, 0, stream>>>(cnt, offs, cursor);
    scatter_kernel<<<256, 256, 0, stream>>>(eidx, cursor, srcs);

    for (int b = 0; b < B_; ++b) {
        const float* hb = h + (size_t)b * N_ * H_;
        pq_gemm<<<(N_ / 32) * 2, 512, 0, stream>>>(hb, w1pq, PQ);
        aggupd_kernel<<<N_ / 16, 512, 0, stream>>>(PQ, srcs, offs, cnt, w2t,
                                                   msg_b1, msg_b2,
                                                   u1t, upd_b1, u2t, upd_b2,
                                                   hb, out + (size_t)b * N_ * H_);
    }
}

// Round 7
// 502.402 us; speedup vs baseline: 1.3034x; 1.3034x over previous
//
#include <hip/hip_runtime.h>
#include <hip/hip_bf16.h>
#include <stdint.h>

#define B_ 2
#define N_ 20000
#define H_ 256
#define E_ 160000
#define M_ 512

typedef short bf16x8 __attribute__((ext_vector_type(8)));
typedef float f32x4 __attribute__((ext_vector_type(4)));

__device__ __forceinline__ unsigned short f2bf(float f) {
    union { float f; unsigned u; } cv; cv.f = f;
    unsigned u = cv.u;
    unsigned r = u + 0x7fffu + ((u >> 16) & 1u);
    return (unsigned short)(r >> 16);
}
__device__ __forceinline__ unsigned pack2(float a, float b) {
    return (unsigned)f2bf(a) | ((unsigned)f2bf(b) << 16);
}
__device__ __forceinline__ float bflo(unsigned p) {
    union { unsigned u; float f; } c; c.u = p << 16; return c.f;
}

// ---------- merged weight transpose/convert ----------
__device__ __forceinline__ void conv_t_one(const float* __restrict__ W,
                                           unsigned short* __restrict__ Wt,
                                           int K, int Ncol, int idx) {
    int n = idx % Ncol;
    int kc = (idx / Ncol) << 3;
    unsigned short t[8];
#pragma unroll
    for (int j = 0; j < 8; ++j) t[j] = f2bf(W[(size_t)(kc + j) * Ncol + n]);
    uint4 v;
    v.x = (unsigned)t[0] | ((unsigned)t[1] << 16);
    v.y = (unsigned)t[2] | ((unsigned)t[3] << 16);
    v.z = (unsigned)t[4] | ((unsigned)t[5] << 16);
    v.w = (unsigned)t[6] | ((unsigned)t[7] << 16);
    *(uint4*)(Wt + (size_t)n * K + kc) = v;
}

// W1pq[jj][kk]: jj<512 -> P col: W1[kk][jj]; jj>=512 -> Q col: W1[kk+256][jj-512]
__device__ __forceinline__ void conv_w1pq_one(const float* __restrict__ W,
                                              unsigned short* __restrict__ Wt, int idx) {
    int jj = idx & 1023;
    int kc = (idx >> 10) << 3;
    int koff = (jj >= 512) ? 256 : 0;
    int j = jj & 511;
    unsigned short t[8];
#pragma unroll
    for (int r = 0; r < 8; ++r) t[r] = f2bf(W[(size_t)(kc + r + koff) * 512 + j]);
    uint4 v;
    v.x = (unsigned)t[0] | ((unsigned)t[1] << 16);
    v.y = (unsigned)t[2] | ((unsigned)t[3] << 16);
    v.z = (unsigned)t[4] | ((unsigned)t[5] << 16);
    v.w = (unsigned)t[6] | ((unsigned)t[7] << 16);
    *(uint4*)(Wt + (size_t)jj * 256 + kc) = v;
}

__global__ void conv_all(const float* __restrict__ mw1, const float* __restrict__ mw2,
                         const float* __restrict__ uw1, const float* __restrict__ uw2,
                         unsigned short* __restrict__ w1pq, unsigned short* __restrict__ w2t,
                         unsigned short* __restrict__ u1t, unsigned short* __restrict__ u2t) {
    int idx = blockIdx.x * blockDim.x + threadIdx.x;
    if (idx < 32768) {
        conv_w1pq_one(mw1, w1pq, idx);
    } else if (idx < 49152) {
        conv_t_one(mw2, w2t, 512, 256, idx - 32768);
    } else if (idx < 81920) {
        conv_t_one(uw1, u1t, 512, 512, idx - 49152);
    } else if (idx < 98304) {
        conv_t_one(uw2, u2t, 512, 256, idx - 81920);
    }
}

// ---------- edge sort by dst (counting sort; store SRC directly) ----------
__global__ void hist_kernel(const int* __restrict__ eidx, int* __restrict__ cnt) {
    for (int e = blockIdx.x * blockDim.x + threadIdx.x; e < E_;
         e += gridDim.x * blockDim.x)
        atomicAdd(cnt + eidx[E_ + e], 1);
}

__global__ void scan_kernel(const int* __restrict__ cnt, int* __restrict__ offs,
                            int* __restrict__ cursor) {
    __shared__ int part[1024];
    int t = threadIdx.x;
    int base_i = t * 20;
    int loc[20];
    int s = 0;
#pragma unroll 20
    for (int i = 0; i < 20; ++i) {
        int idx = base_i + i;
        int v = (idx < N_) ? cnt[idx] : 0;
        loc[i] = s;
        s += v;
    }
    part[t] = s;
    __syncthreads();
    for (int off = 1; off < 1024; off <<= 1) {
        int tmp = (t >= off) ? part[t - off] : 0;
        __syncthreads();
        if (t >= off) part[t] += tmp;
        __syncthreads();
    }
    int base = part[t] - s;
#pragma unroll 20
    for (int i = 0; i < 20; ++i) {
        int idx = base_i + i;
        if (idx < N_) {
            int o = base + loc[i];
            offs[idx] = o;
            cursor[idx] = o;
        }
    }
    if (t == 1023) offs[N_] = part[1023];
}

__global__ void scatter_kernel(const int* __restrict__ eidx, int* __restrict__ cursor,
                               int* __restrict__ srcs) {
    for (int e = blockIdx.x * blockDim.x + threadIdx.x; e < E_;
         e += gridDim.x * blockDim.x) {
        int d = eidx[E_ + e];
        int pos = atomicAdd(cursor + d, 1);
        srcs[pos] = eidx[e];
    }
}

// ---------- PQ = h_b @ [W1a | W1b]  (20000 rows, K=256, 1024 cols) ----------
// block: 64 rows x 512 cols (col-half), 512 threads, wave owns 64 cols -> acc[4][4]=64 VGPR
__global__ __launch_bounds__(512, 4) void pq_gemm(
    const float* __restrict__ hb,
    const unsigned short* __restrict__ W1pq,  // [1024][256] bf16
    unsigned short* __restrict__ PQ) {        // [20000][1024] bf16
    __shared__ char smem[64 * 512];  // 32 KB
    const int tid = threadIdx.x;
    const int tile = blockIdx.x >> 1;
    const int qh = blockIdx.x & 1;
    const int row0 = tile * 64;

    // stage 64 rows x 64 float4 chunks; 512 threads x 8 iters
#pragma unroll
    for (int it = 0; it < 8; ++it) {
        int linear = it * 512 + tid;
        int row = linear >> 6;
        int c4 = linear & 63;
        int grow = row0 + row;
        if (grow >= N_) grow = N_ - 1;
        float4 v = *(const float4*)(hb + (size_t)grow * H_ + c4 * 4);
        int byte = (row * 512 + c4 * 8) ^ ((row & 7) << 4);
        uint2 p;
        p.x = pack2(v.x, v.y);
        p.y = pack2(v.z, v.w);
        *(uint2*)(smem + byte) = p;
    }
    __syncthreads();

    const int lane = tid & 63;
    const int w = tid >> 6;
    const int lo = lane & 15;
    const int hi = lane >> 4;
    const int colw = qh * 512 + w * 64;

    f32x4 acc[4][4];
#pragma unroll
    for (int i = 0; i < 4; ++i)
#pragma unroll
        for (int j = 0; j < 4; ++j) acc[i][j] = (f32x4){0.f, 0.f, 0.f, 0.f};

#pragma unroll
    for (int ks = 0; ks < 256; ks += 32) {
        bf16x8 af[4];
#pragma unroll
        for (int rf = 0; rf < 4; ++rf) {
            int row = rf * 16 + lo;
            int byte = (row * 512 + (ks + 8 * hi) * 2) ^ ((row & 7) << 4);
            af[rf] = *(const bf16x8*)(smem + byte);
        }
#pragma unroll
        for (int cf = 0; cf < 4; ++cf) {
            bf16x8 bfr = *(const bf16x8*)(W1pq + (size_t)(colw + cf * 16 + lo) * 256 + ks + 8 * hi);
#pragma unroll
            for (int rf = 0; rf < 4; ++rf)
                acc[rf][cf] = __builtin_amdgcn_mfma_f32_16x16x32_bf16(af[rf], bfr, acc[rf][cf], 0, 0, 0);
        }
    }

#pragma unroll
    for (int cf = 0; cf < 4; ++cf) {
        int col = colw + cf * 16 + lo;
#pragma unroll
        for (int rf = 0; rf < 4; ++rf) {
#pragma unroll
            for (int r = 0; r < 4; ++r) {
                int row = rf * 16 + hi * 4 + r;
                if (row0 + row < N_)
                    PQ[(size_t)(row0 + row) * 1024 + col] = f2bf(acc[rf][cf][r]);
            }
        }
    }
}

// ---------- fused aggregate + msg-GEMM2 + update MLP ----------
// block: 64 dsts, 512 threads, ONE 64KB LDS buffer -> 2 blocks/CU
// smA cycles: Qb (64x512 bf16) -> hiddensum -> [h|agg] -> hid2
__global__ __launch_bounds__(512, 4) void aggupd_kernel(
    const unsigned short* __restrict__ PQ,
    const int* __restrict__ srcs,
    const int* __restrict__ offs,
    const int* __restrict__ cnt,
    const unsigned short* __restrict__ w2t,   // [256][512]
    const float* __restrict__ mb1,
    const float* __restrict__ mb2,
    const unsigned short* __restrict__ u1t,   // [512][512]
    const float* __restrict__ ub1,
    const unsigned short* __restrict__ u2t,   // [256][512]
    const float* __restrict__ ub2,
    const float* __restrict__ hb,
    float* __restrict__ outb) {
    __shared__ char smA[64 * 1024];
    __shared__ int s_cnt[64];

    const int tid = threadIdx.x;
    const int d0 = blockIdx.x * 64;

    if (tid < 64) {
        int dd = d0 + tid;
        s_cnt[tid] = (dd < N_) ? cnt[dd] : 0;
    }

    // ---- 1. stage Qb = bf16(Q[d] + mb1) -> smA: 64 rows x 64 16B-chunks ----
#pragma unroll
    for (int it = 0; it < 8; ++it) {
        int linear = it * 512 + tid;   // 0..4095 = 64 rows x 64 chunks
        int row = linear >> 6;
        int c8 = linear & 63;
        int dd = d0 + row;
        if (dd >= N_) dd = N_ - 1;
        bf16x8 qv = *(const bf16x8*)(PQ + (size_t)dd * 1024 + 512 + c8 * 8);
        const float* bsrc = mb1 + c8 * 8;
        uint4 v;
        float q0, q1;
        q0 = bflo((unsigned)(unsigned short)qv[0]) + bsrc[0];
        q1 = bflo((unsigned)(unsigned short)qv[1]) + bsrc[1];
        v.x = pack2(q0, q1);
        q0 = bflo((unsigned)(unsigned short)qv[2]) + bsrc[2];
        q1 = bflo((unsigned)(unsigned short)qv[3]) + bsrc[3];
        v.y = pack2(q0, q1);
        q0 = bflo((unsigned)(unsigned short)qv[4]) + bsrc[4];
        q1 = bflo((unsigned)(unsigned short)qv[5]) + bsrc[5];
        v.z = pack2(q0, q1);
        q0 = bflo((unsigned)(unsigned short)qv[6]) + bsrc[6];
        q1 = bflo((unsigned)(unsigned short)qv[7]) + bsrc[7];
        v.w = pack2(q0, q1);
        int byte = (row * 1024 + c8 * 16) ^ ((row & 7) << 4);
        *(uint4*)(smA + byte) = v;
    }
    __syncthreads();

    // ---- 2. edge gather: 8 lanes/dst x 64 cols/lane; qb re-read from LDS ----
    const int dsub = tid >> 3;   // 0..63
    const int part = tid & 7;    // 0..7
    {
        const int d = d0 + dsub;
        int beg = 0, end = 0;
        if (d < N_) { beg = offs[d]; end = offs[d + 1]; }

        float acc[64];
#pragma unroll
        for (int i = 0; i < 64; ++i) acc[i] = 0.f;

        int p = beg;
        for (; p + 1 < end; p += 2) {
            int s0 = srcs[p];
            int s1 = srcs[p + 1];
            const unsigned short* r0 = PQ + (size_t)s0 * 1024;
            const unsigned short* r1 = PQ + (size_t)s1 * 1024;
#pragma unroll
            for (int half = 0; half < 2; ++half) {
                bf16x8 v0[4], v1[4];
#pragma unroll
                for (int c = 0; c < 4; ++c) {
                    int ch = half * 4 + c;
                    v0[c] = *(const bf16x8*)(r0 + (ch * 8 + part) * 8);
                    v1[c] = *(const bf16x8*)(r1 + (ch * 8 + part) * 8);
                }
#pragma unroll
                for (int c = 0; c < 4; ++c) {
                    int ch = half * 4 + c;
                    int byte = (dsub * 1024 + (ch * 8 + part) * 16) ^ ((dsub & 7) << 4);
                    bf16x8 qv = *(const bf16x8*)(smA + byte);
#pragma unroll
                    for (int j = 0; j < 8; ++j) {
                        float q = bflo((unsigned)(unsigned short)qv[j]);
                        acc[ch * 8 + j] += fmaxf(bflo((unsigned)(unsigned short)v0[c][j]) + q, 0.f)
                                         + fmaxf(bflo((unsigned)(unsigned short)v1[c][j]) + q, 0.f);
                    }
                }
            }
        }
        if (p < end) {
            int s0 = srcs[p];
            const unsigned short* r0 = PQ + (size_t)s0 * 1024;
#pragma unroll
            for (int half = 0; half < 2; ++half) {
                bf16x8 v0[4];
#pragma unroll
                for (int c = 0; c < 4; ++c) {
                    int ch = half * 4 + c;
                    v0[c] = *(const bf16x8*)(r0 + (ch * 8 + part) * 8);
                }
#pragma unroll
                for (int c = 0; c < 4; ++c) {
                    int ch = half * 4 + c;
                    int byte = (dsub * 1024 + (ch * 8 + part) * 16) ^ ((dsub & 7) << 4);
                    bf16x8 qv = *(const bf16x8*)(smA + byte);
#pragma unroll
                    for (int j = 0; j < 8; ++j) {
                        float q = bflo((unsigned)(unsigned short)qv[j]);
                        acc[ch * 8 + j] += fmaxf(bflo((unsigned)(unsigned short)v0[c][j]) + q, 0.f);
                    }
                }
            }
        }
        __syncthreads();  // all qb reads done

        // ---- 3. write hiddensum -> smA ----
#pragma unroll
        for (int c = 0; c < 8; ++c) {
            uint4 v;
            v.x = pack2(acc[c * 8 + 0], acc[c * 8 + 1]);
            v.y = pack2(acc[c * 8 + 2], acc[c * 8 + 3]);
            v.z = pack2(acc[c * 8 + 4], acc[c * 8 + 5]);
            v.w = pack2(acc[c * 8 + 6], acc[c * 8 + 7]);
            int byte = (dsub * 1024 + (c * 8 + part) * 16) ^ ((dsub & 7) << 4);
            *(uint4*)(smA + byte) = v;
        }
    }
    __syncthreads();

    const int lane = tid & 63;
    const int w = tid >> 6;
    const int lo = lane & 15;
    const int hi = lane >> 4;

    // ---- 4. phase B: agg = hiddensum @ W2 (held in regs) ----
    f32x4 aB[4][2];
#pragma unroll
    for (int i = 0; i < 4; ++i)
#pragma unroll
        for (int j = 0; j < 2; ++j) aB[i][j] = (f32x4){0.f, 0.f, 0.f, 0.f};
    {
        const int colw = w * 32;
        for (int ks = 0; ks < 512; ks += 32) {
            bf16x8 af[4];
#pragma unroll
            for (int rf = 0; rf < 4; ++rf) {
                int row = rf * 16 + lo;
                int byte = (row * 1024 + (ks + 8 * hi) * 2) ^ ((row & 7) << 4);
                af[rf] = *(const bf16x8*)(smA + byte);
            }
#pragma unroll
            for (int cf = 0; cf < 2; ++cf) {
                bf16x8 bfr = *(const bf16x8*)(w2t + (size_t)(colw + cf * 16 + lo) * 512 + ks + 8 * hi);
#pragma unroll
                for (int rf = 0; rf < 4; ++rf)
                    aB[rf][cf] = __builtin_amdgcn_mfma_f32_16x16x32_bf16(af[rf], bfr, aB[rf][cf], 0, 0, 0);
            }
        }
    }
    __syncthreads();  // hiddensum reads done

    // ---- 5. restage smA = X = [h(bf16) | agg] ----
#pragma unroll
    for (int it = 0; it < 4; ++it) {
        int linear = it * 512 + tid;   // 2048 chunks: 64 rows x 32 chunks
        int row = linear >> 5;
        int c8 = linear & 31;
        int grow = d0 + row;
        if (grow >= N_) grow = N_ - 1;
        const float* src = hb + (size_t)grow * H_ + c8 * 8;
        float4 a = *(const float4*)src;
        float4 b = *(const float4*)(src + 4);
        uint4 v;
        v.x = pack2(a.x, a.y);
        v.y = pack2(a.z, a.w);
        v.z = pack2(b.x, b.y);
        v.w = pack2(b.z, b.w);
        int byte = (row * 1024 + c8 * 16) ^ ((row & 7) << 4);
        *(uint4*)(smA + byte) = v;
    }
    {
        const int colw = w * 32;
#pragma unroll
        for (int cf = 0; cf < 2; ++cf) {
            int col = colw + cf * 16 + lo;
            float bb = mb2[col];
#pragma unroll
            for (int rf = 0; rf < 4; ++rf) {
#pragma unroll
                for (int r = 0; r < 4; ++r) {
                    int row = rf * 16 + hi * 4 + r;
                    float v = aB[rf][cf][r] + (float)s_cnt[row] * bb;
                    int byte = (row * 1024 + (256 + col) * 2) ^ ((row & 7) << 4);
                    *(unsigned short*)(smA + byte) = f2bf(v);
                }
            }
        }
    }
    __syncthreads();

    // ---- 6. phase C: hid2 = relu(X @ U1 + ub1) (held in regs) ----
    f32x4 aC[4][4];
#pragma unroll
    for (int i = 0; i < 4; ++i)
#pragma unroll
        for (int j = 0; j < 4; ++j) aC[i][j] = (f32x4){0.f, 0.f, 0.f, 0.f};
    {
        const int colw = w * 64;
        for (int ks = 0; ks < 512; ks += 32) {
            bf16x8 af[4];
#pragma unroll
            for (int rf = 0; rf < 4; ++rf) {
                int row = rf * 16 + lo;
                int byte = (row * 1024 + (ks + 8 * hi) * 2) ^ ((row & 7) << 4);
                af[rf] = *(const bf16x8*)(smA + byte);
            }
#pragma unroll
            for (int cf = 0; cf < 4; ++cf) {
                bf16x8 bfr = *(const bf16x8*)(u1t + (size_t)(colw + cf * 16 + lo) * 512 + ks + 8 * hi);
#pragma unroll
                for (int rf = 0; rf < 4; ++rf)
                    aC[rf][cf] = __builtin_amdgcn_mfma_f32_16x16x32_bf16(af[rf], bfr, aC[rf][cf], 0, 0, 0);
            }
        }
    }
    __syncthreads();  // X reads done

    // ---- 7. write hid2 -> smA ----
    {
        const int colw = w * 64;
#pragma unroll
        for (int cf = 0; cf < 4; ++cf) {
            int col = colw + cf * 16 + lo;
            float bb = ub1[col];
#pragma unroll
            for (int rf = 0; rf < 4; ++rf) {
#pragma unroll
                for (int r = 0; r < 4; ++r) {
                    float v = fmaxf(aC[rf][cf][r] + bb, 0.f);
                    int row = rf * 16 + hi * 4 + r;
                    int byte = (row * 1024 + col * 2) ^ ((row & 7) << 4);
                    *(unsigned short*)(smA + byte) = f2bf(v);
                }
            }
        }
    }
    __syncthreads();

    // ---- 8. phase D: out = h + hid2 @ U2 + ub2 ----
    {
        const int colw = w * 32;
        f32x4 aD[4][2];
#pragma unroll
        for (int i = 0; i < 4; ++i)
#pragma unroll
            for (int j = 0; j < 2; ++j) aD[i][j] = (f32x4){0.f, 0.f, 0.f, 0.f};

        for (int ks = 0; ks < 512; ks += 32) {
            bf16x8 af[4];
#pragma unroll
            for (int rf = 0; rf < 4; ++rf) {
                int row = rf * 16 + lo;
                int byte = (row * 1024 + (ks + 8 * hi) * 2) ^ ((row & 7) << 4);
                af[rf] = *(const bf16x8*)(smA + byte);
            }
#pragma unroll
            for (int cf = 0; cf < 2; ++cf) {
                bf16x8 bfr = *(const bf16x8*)(u2t + (size_t)(colw + cf * 16 + lo) * 512 + ks + 8 * hi);
#pragma unroll
                for (int rf = 0; rf < 4; ++rf)
                    aD[rf][cf] = __builtin_amdgcn_mfma_f32_16x16x32_bf16(af[rf], bfr, aD[rf][cf], 0, 0, 0);
            }
        }

#pragma unroll
        for (int cf = 0; cf < 2; ++cf) {
            int col = colw + cf * 16 + lo;
            float bb = ub2[col];
#pragma unroll
            for (int rf = 0; rf < 4; ++rf) {
#pragma unroll
                for (int r = 0; r < 4; ++r) {
                    int row = rf * 16 + hi * 4 + r;
                    int grow = d0 + row;
                    if (grow < N_) {
                        size_t o = (size_t)grow * H_ + col;
                        outb[o] = hb[o] + aD[rf][cf][r] + bb;
                    }
                }
            }
        }
    }
}

extern "C" void kernel_launch(void* const* d_in, const int* in_sizes, int n_in,
                              void* d_out, int out_size, void* d_ws, size_t ws_size,
                              hipStream_t stream) {
    const float* h      = (const float*)d_in[0];
    const int*   eidx   = (const int*)d_in[1];
    const float* msg_w1 = (const float*)d_in[2];
    const float* msg_b1 = (const float*)d_in[3];
    const float* msg_w2 = (const float*)d_in[4];
    const float* msg_b2 = (const float*)d_in[5];
    const float* upd_w1 = (const float*)d_in[6];
    const float* upd_b1 = (const float*)d_in[7];
    const float* upd_w2 = (const float*)d_in[8];
    const float* upd_b2 = (const float*)d_in[9];
    float* out = (float*)d_out;

    char* ws = (char*)d_ws;
    size_t off = 0;
    auto alloc = [&](size_t bytes) {
        char* p = ws + off;
        off = (off + bytes + 255) & ~(size_t)255;
        return p;
    };
    unsigned short* PQ   = (unsigned short*)alloc((size_t)N_ * 1024 * 2);  // 41 MB, reused per batch
    unsigned short* w1pq = (unsigned short*)alloc(1024 * 256 * 2);
    unsigned short* w2t  = (unsigned short*)alloc(256 * 512 * 2);
    unsigned short* u1t  = (unsigned short*)alloc(512 * 512 * 2);
    unsigned short* u2t  = (unsigned short*)alloc(256 * 512 * 2);
    int* cnt    = (int*)alloc(N_ * 4);
    int* offs   = (int*)alloc((N_ + 1) * 4);
    int* cursor = (int*)alloc(N_ * 4);
    int* srcs   = (int*)alloc(E_ * 4);
    if (ws_size < off) return;

    hipMemsetAsync(cnt, 0, N_ * 4, stream);
    conv_all<<<384, 256, 0, stream>>>(msg_w1, msg_w2, upd_w1, upd_w2, w1pq, w2t, u1t, u2t);

    hist_kernel<<<256, 256, 0, stream>>>(eidx, cnt);
    scan_kernel<<<1, 1024, 0, stream>>>(cnt, offs, cursor);
    scatter_kernel<<<256, 256, 0, stream>>>(eidx, cursor, srcs);

    const int nblk = (N_ + 63) / 64;   // 313
    for (int b = 0; b < B_; ++b) {
        const float* hb = h + (size_t)b * N_ * H_;
        pq_gemm<<<nblk * 2, 512, 0, stream>>>(hb, w1pq, PQ);
        aggupd_kernel<<<nblk, 512, 0, stream>>>(PQ, srcs, offs, cnt, w2t,
                                                msg_b1, msg_b2,
                                                u1t, upd_b1, u2t, upd_b2,
                                                hb, out + (size_t)b * N_ * H_);
    }
}

// Round 8
// 404.294 us; speedup vs baseline: 1.6196x; 1.2427x over previous
//
#include <hip/hip_runtime.h>
#include <hip/hip_bf16.h>
#include <stdint.h>

#define B_ 2
#define N_ 20000
#define H_ 256
#define E_ 160000
#define M_ 512

typedef short bf16x8 __attribute__((ext_vector_type(8)));
typedef float f32x4 __attribute__((ext_vector_type(4)));

__device__ __forceinline__ unsigned short f2bf(float f) {
    union { float f; unsigned u; } cv; cv.f = f;
    unsigned u = cv.u;
    unsigned r = u + 0x7fffu + ((u >> 16) & 1u);
    return (unsigned short)(r >> 16);
}
__device__ __forceinline__ unsigned pack2(float a, float b) {
    return (unsigned)f2bf(a) | ((unsigned)f2bf(b) << 16);
}
__device__ __forceinline__ float bflo(unsigned p) {
    union { unsigned u; float f; } c; c.u = p << 16; return c.f;
}

// ---------- merged weight transpose/convert ----------
__device__ __forceinline__ void conv_t_one(const float* __restrict__ W,
                                           unsigned short* __restrict__ Wt,
                                           int K, int Ncol, int idx) {
    int n = idx % Ncol;
    int kc = (idx / Ncol) << 3;
    unsigned short t[8];
#pragma unroll
    for (int j = 0; j < 8; ++j) t[j] = f2bf(W[(size_t)(kc + j) * Ncol + n]);
    uint4 v;
    v.x = (unsigned)t[0] | ((unsigned)t[1] << 16);
    v.y = (unsigned)t[2] | ((unsigned)t[3] << 16);
    v.z = (unsigned)t[4] | ((unsigned)t[5] << 16);
    v.w = (unsigned)t[6] | ((unsigned)t[7] << 16);
    *(uint4*)(Wt + (size_t)n * K + kc) = v;
}

// W1pq[jj][kk]: jj<512 -> P col: W1[kk][jj]; jj>=512 -> Q col: W1[kk+256][jj-512]
__device__ __forceinline__ void conv_w1pq_one(const float* __restrict__ W,
                                              unsigned short* __restrict__ Wt, int idx) {
    int jj = idx & 1023;
    int kc = (idx >> 10) << 3;
    int koff = (jj >= 512) ? 256 : 0;
    int j = jj & 511;
    unsigned short t[8];
#pragma unroll
    for (int r = 0; r < 8; ++r) t[r] = f2bf(W[(size_t)(kc + r + koff) * 512 + j]);
    uint4 v;
    v.x = (unsigned)t[0] | ((unsigned)t[1] << 16);
    v.y = (unsigned)t[2] | ((unsigned)t[3] << 16);
    v.z = (unsigned)t[4] | ((unsigned)t[5] << 16);
    v.w = (unsigned)t[6] | ((unsigned)t[7] << 16);
    *(uint4*)(Wt + (size_t)jj * 256 + kc) = v;
}

__global__ void conv_all(const float* __restrict__ mw1, const float* __restrict__ mw2,
                         const float* __restrict__ uw1, const float* __restrict__ uw2,
                         unsigned short* __restrict__ w1pq, unsigned short* __restrict__ w2t,
                         unsigned short* __restrict__ u1t, unsigned short* __restrict__ u2t) {
    int idx = blockIdx.x * blockDim.x + threadIdx.x;
    if (idx < 32768) {
        conv_w1pq_one(mw1, w1pq, idx);
    } else if (idx < 49152) {
        conv_t_one(mw2, w2t, 512, 256, idx - 32768);
    } else if (idx < 81920) {
        conv_t_one(uw1, u1t, 512, 512, idx - 49152);
    } else if (idx < 98304) {
        conv_t_one(uw2, u2t, 512, 256, idx - 81920);
    }
}

// ---------- edge sort by dst (counting sort; store SRC directly) ----------
__global__ void hist_kernel(const int* __restrict__ eidx, int* __restrict__ cnt) {
    for (int e = blockIdx.x * blockDim.x + threadIdx.x; e < E_;
         e += gridDim.x * blockDim.x)
        atomicAdd(cnt + eidx[E_ + e], 1);
}

__global__ void scan_kernel(const int* __restrict__ cnt, int* __restrict__ offs,
                            int* __restrict__ cursor) {
    __shared__ int part[1024];
    int t = threadIdx.x;
    int base_i = t * 20;
    int loc[20];
    int s = 0;
#pragma unroll 20
    for (int i = 0; i < 20; ++i) {
        int idx = base_i + i;
        int v = (idx < N_) ? cnt[idx] : 0;
        loc[i] = s;
        s += v;
    }
    part[t] = s;
    __syncthreads();
    for (int off = 1; off < 1024; off <<= 1) {
        int tmp = (t >= off) ? part[t - off] : 0;
        __syncthreads();
        if (t >= off) part[t] += tmp;
        __syncthreads();
    }
    int base = part[t] - s;
#pragma unroll 20
    for (int i = 0; i < 20; ++i) {
        int idx = base_i + i;
        if (idx < N_) {
            int o = base + loc[i];
            offs[idx] = o;
            cursor[idx] = o;
        }
    }
    if (t == 1023) offs[N_] = part[1023];
}

__global__ void scatter_kernel(const int* __restrict__ eidx, int* __restrict__ cursor,
                               int* __restrict__ srcs) {
    for (int e = blockIdx.x * blockDim.x + threadIdx.x; e < E_;
         e += gridDim.x * blockDim.x) {
        int d = eidx[E_ + e];
        int pos = atomicAdd(cursor + d, 1);
        srcs[pos] = eidx[e];
    }
}

// ---------- PQ = h_b @ [W1a | W1b]  (20000 rows, K=256, 1024 cols) ----------
__global__ __launch_bounds__(512, 4) void pq_gemm(
    const float* __restrict__ hb,
    const unsigned short* __restrict__ W1pq,  // [1024][256] bf16
    unsigned short* __restrict__ PQ) {        // [20000][1024] bf16
    __shared__ char smem[64 * 512];  // 32 KB
    const int tid = threadIdx.x;
    const int tile = blockIdx.x >> 1;
    const int qh = blockIdx.x & 1;
    const int row0 = tile * 64;

#pragma unroll
    for (int it = 0; it < 8; ++it) {
        int linear = it * 512 + tid;
        int row = linear >> 6;
        int c4 = linear & 63;
        int grow = row0 + row;
        if (grow >= N_) grow = N_ - 1;
        float4 v = *(const float4*)(hb + (size_t)grow * H_ + c4 * 4);
        int byte = (row * 512 + c4 * 8) ^ ((row & 7) << 4);
        uint2 p;
        p.x = pack2(v.x, v.y);
        p.y = pack2(v.z, v.w);
        *(uint2*)(smem + byte) = p;
    }
    __syncthreads();

    const int lane = tid & 63;
    const int w = tid >> 6;
    const int lo = lane & 15;
    const int hi = lane >> 4;
    const int colw = qh * 512 + w * 64;

    f32x4 acc[4][4];
#pragma unroll
    for (int i = 0; i < 4; ++i)
#pragma unroll
        for (int j = 0; j < 4; ++j) acc[i][j] = (f32x4){0.f, 0.f, 0.f, 0.f};

#pragma unroll
    for (int ks = 0; ks < 256; ks += 32) {
        bf16x8 af[4];
#pragma unroll
        for (int rf = 0; rf < 4; ++rf) {
            int row = rf * 16 + lo;
            int byte = (row * 512 + (ks + 8 * hi) * 2) ^ ((row & 7) << 4);
            af[rf] = *(const bf16x8*)(smem + byte);
        }
#pragma unroll
        for (int cf = 0; cf < 4; ++cf) {
            bf16x8 bfr = *(const bf16x8*)(W1pq + (size_t)(colw + cf * 16 + lo) * 256 + ks + 8 * hi);
#pragma unroll
            for (int rf = 0; rf < 4; ++rf)
                acc[rf][cf] = __builtin_amdgcn_mfma_f32_16x16x32_bf16(af[rf], bfr, acc[rf][cf], 0, 0, 0);
        }
    }

#pragma unroll
    for (int cf = 0; cf < 4; ++cf) {
        int col = colw + cf * 16 + lo;
#pragma unroll
        for (int rf = 0; rf < 4; ++rf) {
#pragma unroll
            for (int r = 0; r < 4; ++r) {
                int row = rf * 16 + hi * 4 + r;
                if (row0 + row < N_)
                    PQ[(size_t)(row0 + row) * 1024 + col] = f2bf(acc[rf][cf][r]);
            }
        }
    }
}

// ---------- edge gather: one wave per dst; hiddensum -> global (bf16) ----------
// lane covers cols [lane*8, lane*8+8); each edge = one coalesced 1KB wave read
__global__ __launch_bounds__(256, 8) void gather_kernel(
    const unsigned short* __restrict__ PQ,
    const int* __restrict__ srcs,
    const int* __restrict__ offs,
    const float* __restrict__ mb1,
    unsigned short* __restrict__ hsum) {      // [N][512] bf16
    const int lane = threadIdx.x & 63;
    const int nw = (gridDim.x * blockDim.x) >> 6;
    const int wid0 = (blockIdx.x * blockDim.x + threadIdx.x) >> 6;

    float bq[8];
#pragma unroll
    for (int j = 0; j < 8; ++j) bq[j] = mb1[lane * 8 + j];

    for (int d = wid0; d < N_; d += nw) {
        bf16x8 qv = *(const bf16x8*)(PQ + (size_t)d * 1024 + 512 + lane * 8);
        float qb[8];
#pragma unroll
        for (int j = 0; j < 8; ++j)
            qb[j] = bflo((unsigned)(unsigned short)qv[j]) + bq[j];

        float acc[8];
#pragma unroll
        for (int j = 0; j < 8; ++j) acc[j] = 0.f;

        int p = offs[d];
        const int end = offs[d + 1];
        for (; p + 3 < end; p += 4) {
            int s0 = srcs[p];
            int s1 = srcs[p + 1];
            int s2 = srcs[p + 2];
            int s3 = srcs[p + 3];
            bf16x8 v0 = *(const bf16x8*)(PQ + (size_t)s0 * 1024 + lane * 8);
            bf16x8 v1 = *(const bf16x8*)(PQ + (size_t)s1 * 1024 + lane * 8);
            bf16x8 v2 = *(const bf16x8*)(PQ + (size_t)s2 * 1024 + lane * 8);
            bf16x8 v3 = *(const bf16x8*)(PQ + (size_t)s3 * 1024 + lane * 8);
#pragma unroll
            for (int j = 0; j < 8; ++j) {
                float q = qb[j];
                acc[j] += fmaxf(bflo((unsigned)(unsigned short)v0[j]) + q, 0.f)
                        + fmaxf(bflo((unsigned)(unsigned short)v1[j]) + q, 0.f)
                        + fmaxf(bflo((unsigned)(unsigned short)v2[j]) + q, 0.f)
                        + fmaxf(bflo((unsigned)(unsigned short)v3[j]) + q, 0.f);
            }
        }
        for (; p < end; ++p) {
            int s0 = srcs[p];
            bf16x8 v0 = *(const bf16x8*)(PQ + (size_t)s0 * 1024 + lane * 8);
#pragma unroll
            for (int j = 0; j < 8; ++j)
                acc[j] += fmaxf(bflo((unsigned)(unsigned short)v0[j]) + qb[j], 0.f);
        }

        uint4 v;
        v.x = pack2(acc[0], acc[1]);
        v.y = pack2(acc[2], acc[3]);
        v.z = pack2(acc[4], acc[5]);
        v.w = pack2(acc[6], acc[7]);
        *(uint4*)(hsum + (size_t)d * 512 + lane * 8) = v;
    }
}

// ---------- fused msg-GEMM2 + update MLP (64 rows/block) ----------
// smA cycles: hiddensum (staged from global) -> [h|agg] -> hid2
__global__ __launch_bounds__(512, 4) void mlp_kernel(
    const unsigned short* __restrict__ hsum,  // [N][512] bf16
    const int* __restrict__ cnt,
    const unsigned short* __restrict__ w2t,   // [256][512]
    const float* __restrict__ mb2,
    const unsigned short* __restrict__ u1t,   // [512][512]
    const float* __restrict__ ub1,
    const unsigned short* __restrict__ u2t,   // [256][512]
    const float* __restrict__ ub2,
    const float* __restrict__ hb,
    float* __restrict__ outb) {
    __shared__ char smA[64 * 1024];
    __shared__ int s_cnt[64];

    const int tid = threadIdx.x;
    const int d0 = blockIdx.x * 64;

    if (tid < 64) {
        int dd = d0 + tid;
        s_cnt[tid] = (dd < N_) ? cnt[dd] : 0;
    }

    // ---- 1. stage hiddensum -> smA: 64 rows x 64 16B-chunks ----
#pragma unroll
    for (int it = 0; it < 8; ++it) {
        int linear = it * 512 + tid;
        int row = linear >> 6;
        int c8 = linear & 63;
        int dd = d0 + row;
        if (dd >= N_) dd = N_ - 1;
        uint4 v = *(const uint4*)(hsum + (size_t)dd * 512 + c8 * 8);
        int byte = (row * 1024 + c8 * 16) ^ ((row & 7) << 4);
        *(uint4*)(smA + byte) = v;
    }
    __syncthreads();

    const int lane = tid & 63;
    const int w = tid >> 6;
    const int lo = lane & 15;
    const int hi = lane >> 4;

    // ---- 2. phase B: agg = hiddensum @ W2 (held in regs) ----
    f32x4 aB[4][2];
#pragma unroll
    for (int i = 0; i < 4; ++i)
#pragma unroll
        for (int j = 0; j < 2; ++j) aB[i][j] = (f32x4){0.f, 0.f, 0.f, 0.f};
    {
        const int colw = w * 32;
        for (int ks = 0; ks < 512; ks += 32) {
            bf16x8 af[4];
#pragma unroll
            for (int rf = 0; rf < 4; ++rf) {
                int row = rf * 16 + lo;
                int byte = (row * 1024 + (ks + 8 * hi) * 2) ^ ((row & 7) << 4);
                af[rf] = *(const bf16x8*)(smA + byte);
            }
#pragma unroll
            for (int cf = 0; cf < 2; ++cf) {
                bf16x8 bfr = *(const bf16x8*)(w2t + (size_t)(colw + cf * 16 + lo) * 512 + ks + 8 * hi);
#pragma unroll
                for (int rf = 0; rf < 4; ++rf)
                    aB[rf][cf] = __builtin_amdgcn_mfma_f32_16x16x32_bf16(af[rf], bfr, aB[rf][cf], 0, 0, 0);
            }
        }
    }
    __syncthreads();  // hiddensum reads done

    // ---- 3. restage smA = X = [h(bf16) | agg] ----
#pragma unroll
    for (int it = 0; it < 4; ++it) {
        int linear = it * 512 + tid;   // 2048 chunks: 64 rows x 32 chunks
        int row = linear >> 5;
        int c8 = linear & 31;
        int grow = d0 + row;
        if (grow >= N_) grow = N_ - 1;
        const float* src = hb + (size_t)grow * H_ + c8 * 8;
        float4 a = *(const float4*)src;
        float4 b = *(const float4*)(src + 4);
        uint4 v;
        v.x = pack2(a.x, a.y);
        v.y = pack2(a.z, a.w);
        v.z = pack2(b.x, b.y);
        v.w = pack2(b.z, b.w);
        int byte = (row * 1024 + c8 * 16) ^ ((row & 7) << 4);
        *(uint4*)(smA + byte) = v;
    }
    {
        const int colw = w * 32;
#pragma unroll
        for (int cf = 0; cf < 2; ++cf) {
            int col = colw + cf * 16 + lo;
            float bb = mb2[col];
#pragma unroll
            for (int rf = 0; rf < 4; ++rf) {
#pragma unroll
                for (int r = 0; r < 4; ++r) {
                    int row = rf * 16 + hi * 4 + r;
                    float v = aB[rf][cf][r] + (float)s_cnt[row] * bb;
                    int byte = (row * 1024 + (256 + col) * 2) ^ ((row & 7) << 4);
                    *(unsigned short*)(smA + byte) = f2bf(v);
                }
            }
        }
    }
    __syncthreads();

    // ---- 4. phase C: hid2 = relu(X @ U1 + ub1) (held in regs) ----
    f32x4 aC[4][4];
#pragma unroll
    for (int i = 0; i < 4; ++i)
#pragma unroll
        for (int j = 0; j < 4; ++j) aC[i][j] = (f32x4){0.f, 0.f, 0.f, 0.f};
    {
        const int colw = w * 64;
        for (int ks = 0; ks < 512; ks += 32) {
            bf16x8 af[4];
#pragma unroll
            for (int rf = 0; rf < 4; ++rf) {
                int row = rf * 16 + lo;
                int byte = (row * 1024 + (ks + 8 * hi) * 2) ^ ((row & 7) << 4);
                af[rf] = *(const bf16x8*)(smA + byte);
            }
#pragma unroll
            for (int cf = 0; cf < 4; ++cf) {
                bf16x8 bfr = *(const bf16x8*)(u1t + (size_t)(colw + cf * 16 + lo) * 512 + ks + 8 * hi);
#pragma unroll
                for (int rf = 0; rf < 4; ++rf)
                    aC[rf][cf] = __builtin_amdgcn_mfma_f32_16x16x32_bf16(af[rf], bfr, aC[rf][cf], 0, 0, 0);
            }
        }
    }
    __syncthreads();  // X reads done

    // ---- 5. write hid2 -> smA ----
    {
        const int colw = w * 64;
#pragma unroll
        for (int cf = 0; cf < 4; ++cf) {
            int col = colw + cf * 16 + lo;
            float bb = ub1[col];
#pragma unroll
            for (int rf = 0; rf < 4; ++rf) {
#pragma unroll
                for (int r = 0; r < 4; ++r) {
                    float v = fmaxf(aC[rf][cf][r] + bb, 0.f);
                    int row = rf * 16 + hi * 4 + r;
                    int byte = (row * 1024 + col * 2) ^ ((row & 7) << 4);
                    *(unsigned short*)(smA + byte) = f2bf(v);
                }
            }
        }
    }
    __syncthreads();

    // ---- 6. phase D: out = h + hid2 @ U2 + ub2 ----
    {
        const int colw = w * 32;
        f32x4 aD[4][2];
#pragma unroll
        for (int i = 0; i < 4; ++i)
#pragma unroll
            for (int j = 0; j < 2; ++j) aD[i][j] = (f32x4){0.f, 0.f, 0.f, 0.f};

        for (int ks = 0; ks < 512; ks += 32) {
            bf16x8 af[4];
#pragma unroll
            for (int rf = 0; rf < 4; ++rf) {
                int row = rf * 16 + lo;
                int byte = (row * 1024 + (ks + 8 * hi) * 2) ^ ((row & 7) << 4);
                af[rf] = *(const bf16x8*)(smA + byte);
            }
#pragma unroll
            for (int cf = 0; cf < 2; ++cf) {
                bf16x8 bfr = *(const bf16x8*)(u2t + (size_t)(colw + cf * 16 + lo) * 512 + ks + 8 * hi);
#pragma unroll
                for (int rf = 0; rf < 4; ++rf)
                    aD[rf][cf] = __builtin_amdgcn_mfma_f32_16x16x32_bf16(af[rf], bfr, aD[rf][cf], 0, 0, 0);
            }
        }

#pragma unroll
        for (int cf = 0; cf < 2; ++cf) {
            int col = colw + cf * 16 + lo;
            float bb = ub2[col];
#pragma unroll
            for (int rf = 0; rf < 4; ++rf) {
#pragma unroll
                for (int r = 0; r < 4; ++r) {
                    int row = rf * 16 + hi * 4 + r;
                    int grow = d0 + row;
                    if (grow < N_) {
                        size_t o = (size_t)grow * H_ + col;
                        outb[o] = hb[o] + aD[rf][cf][r] + bb;
                    }
                }
            }
        }
    }
}

extern "C" void kernel_launch(void* const* d_in, const int* in_sizes, int n_in,
                              void* d_out, int out_size, void* d_ws, size_t ws_size,
                              hipStream_t stream) {
    const float* h      = (const float*)d_in[0];
    const int*   eidx   = (const int*)d_in[1];
    const float* msg_w1 = (const float*)d_in[2];
    const float* msg_b1 = (const float*)d_in[3];
    const float* msg_w2 = (const float*)d_in[4];
    const float* msg_b2 = (const float*)d_in[5];
    const float* upd_w1 = (const float*)d_in[6];
    const float* upd_b1 = (const float*)d_in[7];
    const float* upd_w2 = (const float*)d_in[8];
    const float* upd_b2 = (const float*)d_in[9];
    float* out = (float*)d_out;

    char* ws = (char*)d_ws;
    size_t off = 0;
    auto alloc = [&](size_t bytes) {
        char* p = ws + off;
        off = (off + bytes + 255) & ~(size_t)255;
        return p;
    };
    unsigned short* PQ   = (unsigned short*)alloc((size_t)N_ * 1024 * 2);  // 41 MB, reused per batch
    unsigned short* hsum = (unsigned short*)alloc((size_t)N_ * 512 * 2);   // 20.5 MB, reused per batch
    unsigned short* w1pq = (unsigned short*)alloc(1024 * 256 * 2);
    unsigned short* w2t  = (unsigned short*)alloc(256 * 512 * 2);
    unsigned short* u1t  = (unsigned short*)alloc(512 * 512 * 2);
    unsigned short* u2t  = (unsigned short*)alloc(256 * 512 * 2);
    int* cnt    = (int*)alloc(N_ * 4);
    int* offs   = (int*)alloc((N_ + 1) * 4);
    int* cursor = (int*)alloc(N_ * 4);
    int* srcs   = (int*)alloc(E_ * 4);
    if (ws_size < off) return;

    hipMemsetAsync(cnt, 0, N_ * 4, stream);
    conv_all<<<384, 256, 0, stream>>>(msg_w1, msg_w2, upd_w1, upd_w2, w1pq, w2t, u1t, u2t);

    hist_kernel<<<256, 256, 0, stream>>>(eidx, cnt);
    scan_kernel<<<1, 1024, 0, stream>>>(cnt, offs, cursor);
    scatter_kernel<<<256, 256, 0, stream>>>(eidx, cursor, srcs);

    const int nblk = (N_ + 63) / 64;   // 313
    for (int b = 0; b < B_; ++b) {
        const float* hb = h + (size_t)b * N_ * H_;
        pq_gemm<<<nblk * 2, 512, 0, stream>>>(hb, w1pq, PQ);
        gather_kernel<<<2048, 256, 0, stream>>>(PQ, srcs, offs, msg_b1, hsum);
        mlp_kernel<<<nblk, 512, 0, stream>>>(hsum, cnt, w2t, msg_b2,
                                             u1t, upd_b1, u2t, upd_b2,
                                             hb, out + (size_t)b * N_ * H_);
    }
}